// Round 1
// baseline (13861.440 us; speedup 1.0000x reference)
//
#include <hip/hip_runtime.h>
#include <stdint.h>
#include <stddef.h>

typedef __attribute__((ext_vector_type(8))) short bf16x8;
typedef __attribute__((ext_vector_type(4))) float f32x4;
typedef unsigned long long u64;

#define NBLK 128
#define NTHR 256
#define S_LEN 512
#define HD   1024
#define IDIM 512

#define MFMA16 __builtin_amdgcn_mfma_f32_16x16x32_bf16

__device__ __forceinline__ float bf2f(uint16_t u){
  union { uint32_t i; float f; } v; v.i = ((uint32_t)u) << 16; return v.f;
}
__device__ __forceinline__ uint16_t f2bf(float f){
  union { float f; uint32_t i; } v; v.f = f;
  uint32_t r = v.i + 0x7fffu + ((v.i >> 16) & 1u);   // round-nearest-even
  return (uint16_t)(r >> 16);
}
__device__ __forceinline__ float sigm(float x){ return 1.0f / (1.0f + __expf(-x)); }
__device__ __forceinline__ float tanh_(float x){
  float t = fminf(fmaxf(2.0f * x, -30.0f), 30.0f);
  float e = __expf(t);
  return (e - 1.0f) / (e + 1.0f);
}

// Split 8 consecutive fp32 into bf16 hi + bf16 lo (residual) fragments.
__device__ __forceinline__ void split8(const float* p, bf16x8& hi8, bf16x8& lo8){
  const float4 a = *(const float4*)p;
  const float4 b = *(const float4*)(p + 4);
  float v[8] = {a.x, a.y, a.z, a.w, b.x, b.y, b.z, b.w};
  #pragma unroll
  for (int j = 0; j < 8; ++j){
    uint16_t h = f2bf(v[j]);
    hi8[j] = (short)h;
    lo8[j] = (short)f2bf(v[j] - bf2f(h));
  }
}

// Coherent (agent-scope, sc1 = bypass stale L1/L2, served by LLC) load of an
// 8-col h fragment stored as packed dwords (hi in [15:0], lo in [31:16]).
// De-interleave with v_perm_b32 (compile-time selectors; lo dword = src1).
__device__ __forceinline__ void load_hfrag(const uint32_t* p, bf16x8& Ah, bf16x8& Al){
  u64 d0 = __hip_atomic_load((const u64*)(p + 0), __ATOMIC_RELAXED, __HIP_MEMORY_SCOPE_AGENT);
  u64 d1 = __hip_atomic_load((const u64*)(p + 2), __ATOMIC_RELAXED, __HIP_MEMORY_SCOPE_AGENT);
  u64 d2 = __hip_atomic_load((const u64*)(p + 4), __ATOMIC_RELAXED, __HIP_MEMORY_SCOPE_AGENT);
  u64 d3 = __hip_atomic_load((const u64*)(p + 6), __ATOMIC_RELAXED, __HIP_MEMORY_SCOPE_AGENT);
  uint32_t q0 = (uint32_t)d0, q1 = (uint32_t)(d0 >> 32);
  uint32_t q2 = (uint32_t)d1, q3 = (uint32_t)(d1 >> 32);
  uint32_t q4 = (uint32_t)d2, q5 = (uint32_t)(d2 >> 32);
  uint32_t q6 = (uint32_t)d3, q7 = (uint32_t)(d3 >> 32);
  union { uint32_t u[4]; bf16x8 v; } H, L;
  H.u[0] = __builtin_amdgcn_perm(q1, q0, 0x05040100u);
  L.u[0] = __builtin_amdgcn_perm(q1, q0, 0x07060302u);
  H.u[1] = __builtin_amdgcn_perm(q3, q2, 0x05040100u);
  L.u[1] = __builtin_amdgcn_perm(q3, q2, 0x07060302u);
  H.u[2] = __builtin_amdgcn_perm(q5, q4, 0x05040100u);
  L.u[2] = __builtin_amdgcn_perm(q5, q4, 0x07060302u);
  H.u[3] = __builtin_amdgcn_perm(q7, q6, 0x05040100u);
  L.u[3] = __builtin_amdgcn_perm(q7, q6, 0x07060302u);
  Ah = H.v; Al = L.v;
}

// Persistent LSTM. 128 blocks; block f owns h-cols [8f,8f+8).
// Gate tiles (N=16): tile0 = [H1|H2] (forget|input), tile1 = [H3|H4] (cand|out).
// K split across 4 waves (h:256 each, x:128 each); weights live in VGPRs as
// bf16 hi+lo pairs; A*W done with 3 MFMAs (Ahi*Whi + Alo*Whi + Ahi*Wlo).
//
// Sync (this revision): NO __threadfence anywhere. The old fences lowered to
// per-block L2 writeback/invalidate walks — 32 cache-wide maintenance ops per
// XCD per step, the suspected 20 µs/step serializer (and they killed x's L2
// residency). Instead the *communicated* data itself is coherent:
//   publish:  h packed (hi|lo) dword -> atomic relaxed AGENT store (sc1,
//             write-through to LLC), per-wave s_waitcnt vmcnt(0), barrier,
//             then flag store (same proven-coherent primitive as before).
//   consume:  poll flags, barrier, then 64-bit atomic relaxed AGENT loads
//             (sc1, bypass stale L1/L2 — same primitive the poll relies on).
__global__ void __launch_bounds__(NTHR, 1) lstm_persist(
    const float* __restrict__ x,
    const float* __restrict__ X1, const float* __restrict__ H1, const float* __restrict__ b1,
    const float* __restrict__ X2, const float* __restrict__ H2, const float* __restrict__ b2,
    const float* __restrict__ X3, const float* __restrict__ H3, const float* __restrict__ b3,
    const float* __restrict__ X4, const float* __restrict__ H4, const float* __restrict__ b4,
    float* __restrict__ out, uint32_t* hb32, int* done)
{
  __shared__ float part[4][64][36];   // stride 36: quad row-step 4*36 ≡ 16 (mod 32) → 2-way only
  const int tid  = threadIdx.x;
  const int w    = tid >> 6;          // wave 0..3
  const int L    = tid & 63;
  const int c    = L & 15;            // MFMA n / A-row-in-tile
  const int quad = L >> 4;
  const int cc   = c & 7;
  const int f    = blockIdx.x;
  const int colh = f * 8 + cc;        // owned h-column
  const bool hiHalf = (c >= 8);

  const float* W0 = hiHalf ? H2 : H1;
  const float* W1 = hiHalf ? H4 : H3;
  const float* V0 = hiHalf ? X2 : X1;
  const float* V1 = hiHalf ? X4 : X3;
  const float bias0 = (hiHalf ? b2 : b1)[colh];
  const float bias1 = (hiHalf ? b4 : b3)[colh];

  // --- one-time: weight fragments (B layout: n = lane&15, k = quad*8 + j) ---
  bf16x8 BhH0[8], BhL0[8], BhH1[8], BhL1[8];
  #pragma unroll
  for (int kk = 0; kk < 8; ++kk){
    const int kb = w*256 + kk*32 + quad*8;
    bf16x8 h0, l0, h1, l1;
    #pragma unroll
    for (int j = 0; j < 8; ++j){
      float w0 = W0[(size_t)(kb + j)*HD + colh];
      uint16_t a = f2bf(w0); h0[j] = (short)a; l0[j] = (short)f2bf(w0 - bf2f(a));
      float w1 = W1[(size_t)(kb + j)*HD + colh];
      uint16_t b_ = f2bf(w1); h1[j] = (short)b_; l1[j] = (short)f2bf(w1 - bf2f(b_));
    }
    BhH0[kk] = h0; BhL0[kk] = l0; BhH1[kk] = h1; BhL1[kk] = l1;
  }
  bf16x8 BxH0[4], BxL0[4], BxH1[4], BxL1[4];
  #pragma unroll
  for (int kk = 0; kk < 4; ++kk){
    const int kb = w*128 + kk*32 + quad*8;
    bf16x8 h0, l0, h1, l1;
    #pragma unroll
    for (int j = 0; j < 8; ++j){
      float w0 = V0[(size_t)(kb + j)*HD + colh];
      uint16_t a = f2bf(w0); h0[j] = (short)a; l0[j] = (short)f2bf(w0 - bf2f(a));
      float w1 = V1[(size_t)(kb + j)*HD + colh];
      uint16_t b_ = f2bf(w1); h1[j] = (short)b_; l1[j] = (short)f2bf(w1 - bf2f(b_));
    }
    BxH0[kk] = h0; BxL0[kk] = l0; BxH1[kk] = h1; BxL1[kk] = l1;
  }

  float cst[4] = {0.f, 0.f, 0.f, 0.f};

  #pragma unroll 1
  for (int t = 0; t < S_LEN; ++t){
    const int p = t & 1;
    f32x4 acc0[4], acc1[4];
    #pragma unroll
    for (int m = 0; m < 4; ++m){
      acc0[m] = (f32x4){0.f,0.f,0.f,0.f};
      acc1[m] = (f32x4){0.f,0.f,0.f,0.f};
    }

    // ---- x-phase: x_t @ Xcat slice (independent of h; runs before the wait;
    //      x now stays L2-resident since nothing invalidates it) ----
    #pragma unroll
    for (int kk = 0; kk < 4; ++kk){
      #pragma unroll
      for (int m = 0; m < 4; ++m){
        const float* xp = x + ((size_t)(16*m + c)*S_LEN + t)*IDIM + w*128 + kk*32 + quad*8;
        bf16x8 Ah, Al; split8(xp, Ah, Al);
        acc0[m] = MFMA16(Ah, BxH0[kk], acc0[m], 0, 0, 0);
        acc0[m] = MFMA16(Al, BxH0[kk], acc0[m], 0, 0, 0);
        acc0[m] = MFMA16(Ah, BxL0[kk], acc0[m], 0, 0, 0);
        acc1[m] = MFMA16(Ah, BxH1[kk], acc1[m], 0, 0, 0);
        acc1[m] = MFMA16(Al, BxH1[kk], acc1[m], 0, 0, 0);
        acc1[m] = MFMA16(Ah, BxL1[kk], acc1[m], 0, 0, 0);
      }
    }

    // ---- wait: all blocks must have published h_t (done[b] >= t); no fence —
    //      h loads below are themselves coherent ----
    if (t > 0){
      if (tid < NBLK){
        while (__hip_atomic_load(&done[tid*32], __ATOMIC_RELAXED, __HIP_MEMORY_SCOPE_AGENT) < t)
          __builtin_amdgcn_s_sleep(1);
      }
      __syncthreads();
    }

    // ---- h-phase: h_t @ Hcat slice; coherent 64-bit loads of packed hi|lo ----
    const uint32_t* hb = hb32 + (size_t)p * (64*HD);
    #pragma unroll
    for (int kk = 0; kk < 8; ++kk){
      #pragma unroll
      for (int m = 0; m < 4; ++m){
        const uint32_t* hp = hb + (size_t)(16*m + c)*HD + w*256 + kk*32 + quad*8;
        bf16x8 Ah, Al;
        load_hfrag(hp, Ah, Al);
        acc0[m] = MFMA16(Ah, BhH0[kk], acc0[m], 0, 0, 0);
        acc0[m] = MFMA16(Al, BhH0[kk], acc0[m], 0, 0, 0);
        acc0[m] = MFMA16(Ah, BhL0[kk], acc0[m], 0, 0, 0);
        acc1[m] = MFMA16(Ah, BhH1[kk], acc1[m], 0, 0, 0);
        acc1[m] = MFMA16(Al, BhH1[kk], acc1[m], 0, 0, 0);
        acc1[m] = MFMA16(Ah, BhL1[kk], acc1[m], 0, 0, 0);
      }
    }

    // ---- stash partials (C/D: col = lane&15, row = quad*4 + reg) ----
    #pragma unroll
    for (int m = 0; m < 4; ++m){
      #pragma unroll
      for (int r = 0; r < 4; ++r){
        part[w][16*m + quad*4 + r][c]      = acc0[m][r];
        part[w][16*m + quad*4 + r][16 + c] = acc1[m][r];
      }
    }
    __syncthreads();

    // ---- cross-wave K-reduction; wave w handles batch rows [16w,16w+16) ----
    float g0[4], g1[4];
    #pragma unroll
    for (int r = 0; r < 4; ++r){
      const int row = 16*w + quad*4 + r;
      float a = bias0, b = bias1;
      #pragma unroll
      for (int ww = 0; ww < 4; ++ww){
        a += part[ww][row][c];
        b += part[ww][row][16 + c];
      }
      g0[r] = a; g1[r] = b;
    }

    // ---- gates (lane c<8 holds forget/cand; partner c+8 holds input/output) ----
    uint32_t* hw = hb32 + (size_t)(p^1) * (64*HD);
    float hv[4];
    #pragma unroll
    for (int r = 0; r < 4; ++r){
      float gf = g0[r];
      float gi = __shfl_xor(g0[r], 8, 64);
      float gc = g1[r];
      float go = __shfl_xor(g1[r], 8, 64);
      float cn = cst[r] * sigm(gf) + sigm(gi) * tanh_(gc);
      cst[r] = cn;
      hv[r] = tanh_(cn) * sigm(go);
    }
    if (!hiHalf){
      #pragma unroll
      for (int r = 0; r < 4; ++r){
        const int batch = 16*w + quad*4 + r;
        uint16_t hh = f2bf(hv[r]);
        uint16_t hl = f2bf(hv[r] - bf2f(hh));
        uint32_t pk = (uint32_t)hh | ((uint32_t)hl << 16);
        // write-through (sc1) store: visible at LLC, no L2 flush needed
        __hip_atomic_store(&hw[(size_t)batch*HD + colh], pk,
                           __ATOMIC_RELAXED, __HIP_MEMORY_SCOPE_AGENT);
      }
    }

    // ---- publish: per-wave drain of the write-through h stores, converge,
    //      then flag store. No cache maintenance. ----
    asm volatile("s_waitcnt vmcnt(0)" ::: "memory");
    __syncthreads();
    if (tid == 0)
      __hip_atomic_store(&done[f*32], t + 1, __ATOMIC_RELAXED, __HIP_MEMORY_SCOPE_AGENT);

    // ---- out stores moved OFF the critical publish path (drained by next
    //      step's vmcnt(0); nobody reads out until kernel end) ----
    if (!hiHalf){
      #pragma unroll
      for (int r = 0; r < 4; ++r){
        const int batch = 16*w + quad*4 + r;
        __builtin_nontemporal_store(hv[r], &out[(size_t)(batch*S_LEN + t)*HD + colh]);
      }
    }
  }
}

extern "C" void kernel_launch(void* const* d_in, const int* in_sizes, int n_in,
                              void* d_out, int out_size, void* d_ws, size_t ws_size,
                              hipStream_t stream) {
  const float* x  = (const float*)d_in[0];
  const float* X1 = (const float*)d_in[1];
  const float* H1 = (const float*)d_in[2];
  const float* b1 = (const float*)d_in[3];
  const float* X2 = (const float*)d_in[4];
  const float* H2 = (const float*)d_in[5];
  const float* b2 = (const float*)d_in[6];
  const float* X3 = (const float*)d_in[7];
  const float* H3 = (const float*)d_in[8];
  const float* b3 = (const float*)d_in[9];
  const float* X4 = (const float*)d_in[10];
  const float* H4 = (const float*)d_in[11];
  const float* b4 = (const float*)d_in[12];
  float* out = (float*)d_out;

  // ws: hb32 [2][64][1024] packed (hi|lo) dwords (524288 B) | done[128] @128B stride
  uint32_t* hb32 = (uint32_t*)d_ws;
  int* done      = (int*)((char*)d_ws + 524288);
  hipMemsetAsync(d_ws, 0, 524288 + 16384, stream);   // h0 = 0 (hi|lo packed), flags = 0

  hipLaunchKernelGGL(lstm_persist, dim3(NBLK), dim3(NTHR), 0, stream,
                     x, X1, H1, b1, X2, H2, b2, X3, H3, b3, X4, H4, b4,
                     out, hb32, done);
}

// Round 2
// 7553.613 us; speedup vs baseline: 1.8351x; 1.8351x over previous
//
#include <hip/hip_runtime.h>
#include <stdint.h>
#include <stddef.h>

typedef __attribute__((ext_vector_type(8))) short bf16x8;
typedef __attribute__((ext_vector_type(4))) float f32x4;

#define NBLK 128
#define NTHR 512          // 8 waves: 2 waves/SIMD TLP, K split 8 ways
#define S_LEN 512
#define HD   1024
#define IDIM 512

#define MFMA16 __builtin_amdgcn_mfma_f32_16x16x32_bf16

__device__ __forceinline__ float bf2f(uint16_t u){
  union { uint32_t i; float f; } v; v.i = ((uint32_t)u) << 16; return v.f;
}
__device__ __forceinline__ uint16_t f2bf(float f){
  union { float f; uint32_t i; } v; v.f = f;
  uint32_t r = v.i + 0x7fffu + ((v.i >> 16) & 1u);   // round-nearest-even
  return (uint16_t)(r >> 16);
}
__device__ __forceinline__ float sigm(float x){ return 1.0f / (1.0f + __expf(-x)); }
__device__ __forceinline__ float tanh_(float x){
  float t = fminf(fmaxf(2.0f * x, -30.0f), 30.0f);
  float e = __expf(t);
  return (e - 1.0f) / (e + 1.0f);
}

// Split 8 consecutive fp32 into bf16 hi + bf16 lo (residual) fragments.
__device__ __forceinline__ void split8(const float* p, bf16x8& hi8, bf16x8& lo8){
  const float4 a = *(const float4*)p;
  const float4 b = *(const float4*)(p + 4);
  float v[8] = {a.x, a.y, a.z, a.w, b.x, b.y, b.z, b.w};
  #pragma unroll
  for (int j = 0; j < 8; ++j){
    uint16_t h = f2bf(v[j]);
    hi8[j] = (short)h;
    lo8[j] = (short)f2bf(v[j] - bf2f(h));
  }
}

// Coherent 16B load: sc0 sc1 -> miss L1 and per-XCD L2, served by LLC (the
// coherence point the round-1 atomics validated). Volatile asm keeps program
// order vs other volatile asm (our issue batches + counted waitcnts).
__device__ __forceinline__ void cload16(const uint16_t* p, bf16x8& d){
  asm volatile("global_load_dwordx4 %0, %1, off sc0 sc1" : "=v"(d) : "v"(p));
}
__device__ __forceinline__ void cstore16b(uint16_t* p, uint32_t v){
  asm volatile("global_store_short %0, %1, off sc0 sc1" :: "v"(p), "v"(v) : "memory");
}

// Persistent LSTM. 128 blocks x 8 waves; block f owns h-cols [8f,8f+8).
// Gate tiles (N=16): tile0 = [H1|H2] (forget|input), tile1 = [H3|H4] (cand|out).
// K split across 8 waves (h:128 each, x:64 each); weights in VGPRs as bf16
// hi+lo pairs (96 VGPR); A*W via 3 MFMAs (Ahi*Whi + Alo*Whi + Ahi*Wlo).
//
// Round-2 change: the bottleneck was per-wave load-latency serialization
// (32 dependent ~800cy stops/step), not coherence ops. Now: 2 waves/SIMD,
// 16 h-fragments/wave, issued 8-at-a-time with next-batch prefetch and
// counted s_waitcnt vmcnt(8) so each batch's latency hides under the
// previous batch's MFMAs.
__global__ void __launch_bounds__(NTHR, 2) lstm_persist(
    const float* __restrict__ x,
    const float* __restrict__ X1, const float* __restrict__ H1, const float* __restrict__ b1,
    const float* __restrict__ X2, const float* __restrict__ H2, const float* __restrict__ b2,
    const float* __restrict__ X3, const float* __restrict__ H3, const float* __restrict__ b3,
    const float* __restrict__ X4, const float* __restrict__ H4, const float* __restrict__ b4,
    float* __restrict__ out, uint16_t* hbhi, uint16_t* hblo, int* done)
{
  __shared__ float part[8][64][36];
  const int tid  = threadIdx.x;
  const int w    = tid >> 6;          // wave 0..7
  const int L    = tid & 63;
  const int c    = L & 15;            // MFMA n / A-row-in-tile
  const int quad = L >> 4;
  const int cc   = c & 7;
  const int f    = blockIdx.x;
  const int colh = f * 8 + cc;        // owned h-column
  const bool hiHalf = (c >= 8);

  const float* W0 = hiHalf ? H2 : H1;
  const float* W1 = hiHalf ? H4 : H3;
  const float* V0 = hiHalf ? X2 : X1;
  const float* V1 = hiHalf ? X4 : X3;
  const float bias0 = (hiHalf ? b2 : b1)[colh];
  const float bias1 = (hiHalf ? b4 : b3)[colh];

  // --- one-time: weight fragments (B layout: n = lane&15, k = quad*8 + j) ---
  bf16x8 BhH0[4], BhL0[4], BhH1[4], BhL1[4];
  #pragma unroll
  for (int kk = 0; kk < 4; ++kk){
    const int kb = w*128 + kk*32 + quad*8;
    bf16x8 h0, l0, h1, l1;
    #pragma unroll
    for (int j = 0; j < 8; ++j){
      float w0 = W0[(size_t)(kb + j)*HD + colh];
      uint16_t a = f2bf(w0); h0[j] = (short)a; l0[j] = (short)f2bf(w0 - bf2f(a));
      float w1 = W1[(size_t)(kb + j)*HD + colh];
      uint16_t b_ = f2bf(w1); h1[j] = (short)b_; l1[j] = (short)f2bf(w1 - bf2f(b_));
    }
    BhH0[kk] = h0; BhL0[kk] = l0; BhH1[kk] = h1; BhL1[kk] = l1;
  }
  bf16x8 BxH0[2], BxL0[2], BxH1[2], BxL1[2];
  #pragma unroll
  for (int kk = 0; kk < 2; ++kk){
    const int kb = w*64 + kk*32 + quad*8;
    bf16x8 h0, l0, h1, l1;
    #pragma unroll
    for (int j = 0; j < 8; ++j){
      float w0 = V0[(size_t)(kb + j)*HD + colh];
      uint16_t a = f2bf(w0); h0[j] = (short)a; l0[j] = (short)f2bf(w0 - bf2f(a));
      float w1 = V1[(size_t)(kb + j)*HD + colh];
      uint16_t b_ = f2bf(w1); h1[j] = (short)b_; l1[j] = (short)f2bf(w1 - bf2f(b_));
    }
    BxH0[kk] = h0; BxL0[kk] = l0; BxH1[kk] = h1; BxL1[kk] = l1;
  }

  float cst[2] = {0.f, 0.f};

  #pragma unroll 1
  for (int t = 0; t < S_LEN; ++t){
    const int p = t & 1;
    f32x4 acc0[4], acc1[4];
    #pragma unroll
    for (int m = 0; m < 4; ++m){
      acc0[m] = (f32x4){0.f,0.f,0.f,0.f};
      acc1[m] = (f32x4){0.f,0.f,0.f,0.f};
    }

    // ---- x-phase: x_t @ Xcat slice (independent of h; overlaps the wait) ----
    #pragma unroll
    for (int kk = 0; kk < 2; ++kk){
      #pragma unroll
      for (int m = 0; m < 4; ++m){
        const float* xp = x + ((size_t)(16*m + c)*S_LEN + t)*IDIM + w*64 + kk*32 + quad*8;
        bf16x8 Ah, Al; split8(xp, Ah, Al);
        acc0[m] = MFMA16(Ah, BxH0[kk], acc0[m], 0, 0, 0);
        acc0[m] = MFMA16(Al, BxH0[kk], acc0[m], 0, 0, 0);
        acc0[m] = MFMA16(Ah, BxL0[kk], acc0[m], 0, 0, 0);
        acc1[m] = MFMA16(Ah, BxH1[kk], acc1[m], 0, 0, 0);
        acc1[m] = MFMA16(Al, BxH1[kk], acc1[m], 0, 0, 0);
        acc1[m] = MFMA16(Ah, BxL1[kk], acc1[m], 0, 0, 0);
      }
    }

    // ---- wait: all blocks must have published h_t (done[b] >= t) ----
    if (t > 0){
      if (tid < NBLK){
        while (__hip_atomic_load(&done[tid*32], __ATOMIC_RELAXED, __HIP_MEMORY_SCOPE_AGENT) < t)
          __builtin_amdgcn_s_sleep(1);
      }
      __syncthreads();
    }

    // ---- h-phase: batched coherent loads with counted-vmcnt pipelining ----
    const uint16_t* hbH = hbhi + (size_t)p * (64*HD);
    const uint16_t* hbL = hblo + (size_t)p * (64*HD);
    {
      bf16x8 AH[2][4], AL[2][4];
      #define H_OFF(m, kk) ((size_t)(16*(m) + c)*HD + w*128 + (kk)*32 + quad*8)
      #define ISSUE_M(buf, m) do { \
        _Pragma("unroll") \
        for (int kk = 0; kk < 4; ++kk){ \
          cload16(hbH + H_OFF(m, kk), AH[buf][kk]); \
          cload16(hbL + H_OFF(m, kk), AL[buf][kk]); \
        } } while(0)

      // zero the vmem count so the counted waits below are exact
      asm volatile("s_waitcnt vmcnt(0)" ::: "memory");
      ISSUE_M(0, 0);
      #pragma unroll
      for (int m = 0; m < 4; ++m){
        const int buf = m & 1;
        if (m < 3){
          ISSUE_M(buf ^ 1, m + 1);
          asm volatile("s_waitcnt vmcnt(8)" ::: "memory");  // batch m done, m+1 in flight
        } else {
          asm volatile("s_waitcnt vmcnt(0)" ::: "memory");
        }
        __builtin_amdgcn_sched_barrier(0);                  // rule #18: pin MFMAs after wait
        #pragma unroll
        for (int kk = 0; kk < 4; ++kk){
          acc0[m] = MFMA16(AH[buf][kk], BhH0[kk], acc0[m], 0, 0, 0);
          acc0[m] = MFMA16(AL[buf][kk], BhH0[kk], acc0[m], 0, 0, 0);
          acc0[m] = MFMA16(AH[buf][kk], BhL0[kk], acc0[m], 0, 0, 0);
          acc1[m] = MFMA16(AH[buf][kk], BhH1[kk], acc1[m], 0, 0, 0);
          acc1[m] = MFMA16(AL[buf][kk], BhH1[kk], acc1[m], 0, 0, 0);
          acc1[m] = MFMA16(AH[buf][kk], BhL1[kk], acc1[m], 0, 0, 0);
        }
      }
      #undef ISSUE_M
      #undef H_OFF
    }

    // ---- stash partials (C/D: col = lane&15, row = quad*4 + reg) ----
    #pragma unroll
    for (int m = 0; m < 4; ++m){
      #pragma unroll
      for (int r = 0; r < 4; ++r){
        part[w][16*m + quad*4 + r][c]      = acc0[m][r];
        part[w][16*m + quad*4 + r][16 + c] = acc1[m][r];
      }
    }
    __syncthreads();

    // ---- cross-wave K-reduction; wave w handles batch rows [8w,8w+8) ----
    // read rows 8w + quad*2 + r2: quad stride = 2*36 ≡ 8 (mod 32) → 2-way only
    float g0[2], g1[2];
    #pragma unroll
    for (int r2 = 0; r2 < 2; ++r2){
      const int row = 8*w + quad*2 + r2;
      float a = bias0, b = bias1;
      #pragma unroll
      for (int ww = 0; ww < 8; ++ww){
        a += part[ww][row][c];
        b += part[ww][row][16 + c];
      }
      g0[r2] = a; g1[r2] = b;
    }

    // ---- gates (lane c<8 holds forget/cand; partner c+8 holds input/output) ----
    uint16_t* hwH = hbhi + (size_t)(p^1) * (64*HD);
    uint16_t* hwL = hblo + (size_t)(p^1) * (64*HD);
    float hv[2];
    #pragma unroll
    for (int r2 = 0; r2 < 2; ++r2){
      float gf = g0[r2];
      float gi = __shfl_xor(g0[r2], 8, 64);
      float gc = g1[r2];
      float go = __shfl_xor(g1[r2], 8, 64);
      float cn = cst[r2] * sigm(gf) + sigm(gi) * tanh_(gc);
      cst[r2] = cn;
      hv[r2] = tanh_(cn) * sigm(go);
    }
    if (!hiHalf){
      #pragma unroll
      for (int r2 = 0; r2 < 2; ++r2){
        const int batch = 8*w + quad*2 + r2;
        uint16_t hh = f2bf(hv[r2]);
        uint16_t hl = f2bf(hv[r2] - bf2f(hh));
        cstore16b(hwH + (size_t)batch*HD + colh, (uint32_t)hh);
        cstore16b(hwL + (size_t)batch*HD + colh, (uint32_t)hl);
      }
    }

    // ---- publish: drain write-through h stores, converge, flag store ----
    asm volatile("s_waitcnt vmcnt(0)" ::: "memory");
    __syncthreads();
    if (tid == 0)
      __hip_atomic_store(&done[f*32], t + 1, __ATOMIC_RELAXED, __HIP_MEMORY_SCOPE_AGENT);

    // ---- out stores OFF the critical publish path ----
    if (!hiHalf){
      #pragma unroll
      for (int r2 = 0; r2 < 2; ++r2){
        const int batch = 8*w + quad*2 + r2;
        __builtin_nontemporal_store(hv[r2], &out[(size_t)(batch*S_LEN + t)*HD + colh]);
      }
    }
  }
}

extern "C" void kernel_launch(void* const* d_in, const int* in_sizes, int n_in,
                              void* d_out, int out_size, void* d_ws, size_t ws_size,
                              hipStream_t stream) {
  const float* x  = (const float*)d_in[0];
  const float* X1 = (const float*)d_in[1];
  const float* H1 = (const float*)d_in[2];
  const float* b1 = (const float*)d_in[3];
  const float* X2 = (const float*)d_in[4];
  const float* H2 = (const float*)d_in[5];
  const float* b2 = (const float*)d_in[6];
  const float* X3 = (const float*)d_in[7];
  const float* H3 = (const float*)d_in[8];
  const float* b3 = (const float*)d_in[9];
  const float* X4 = (const float*)d_in[10];
  const float* H4 = (const float*)d_in[11];
  const float* b4 = (const float*)d_in[12];
  float* out = (float*)d_out;

  // ws: hbhi [2][64][1024] bf16 (262144 B) | hblo same | done[128] @128B stride
  uint16_t* hbhi = (uint16_t*)d_ws;
  uint16_t* hblo = (uint16_t*)((char*)d_ws + 262144);
  int* done      = (int*)((char*)d_ws + 524288);
  hipMemsetAsync(d_ws, 0, 524288 + 16384, stream);   // h0 = 0 (hi/lo), flags = 0

  hipLaunchKernelGGL(lstm_persist, dim3(NBLK), dim3(NTHR), 0, stream,
                     x, X1, H1, b1, X2, H2, b2, X3, H3, b3, X4, H4, b4,
                     out, hbhi, hblo, done);
}